// Round 5
// baseline (397.350 us; speedup 1.0000x reference)
//
#include <hip/hip_runtime.h>

typedef unsigned int u32;
typedef __bf16 bf16;
typedef bf16 bf16x2 __attribute__((ext_vector_type(2)));
typedef bf16 bf16x4 __attribute__((ext_vector_type(4)));
typedef bf16 bf16x8 __attribute__((ext_vector_type(8)));
typedef float f32x4 __attribute__((ext_vector_type(4)));
typedef float f32x16 __attribute__((ext_vector_type(16)));
typedef u32 u32x4 __attribute__((ext_vector_type(4)));

#define T_ 2048
#define D_ 2048
#define H_ 16
#define HD_ 128
#define SCALE_ 0.022097086912079608f  // 2048^-0.5 (full embed_dim per reference)
#define LOG2E_ 1.4426950408889634f

typedef __attribute__((address_space(1))) u32 gu32;
typedef __attribute__((address_space(3))) u32 lu32;

__device__ __forceinline__ void gload_lds16(const void* g, void* l) {
  __builtin_amdgcn_global_load_lds((gu32*)(void*)g, (lu32*)l, 16, 0, 0);
}

__device__ __forceinline__ u32 packbf(float a, float b) {
  union { bf16x2 v; u32 u; } c;
  c.v.x = (bf16)a; c.v.y = (bf16)b;
  return c.u;
}

// ---------------- cast x: fp32 -> bf16 ----------------
__global__ void cast_x_kernel(const float* __restrict__ x, bf16* __restrict__ xb) {
  int i = blockIdx.x * 256 + threadIdx.x;
  float4 v = ((const float4*)x)[i];
  bf16x4 o;
  o.x = (bf16)v.x; o.y = (bf16)v.y; o.z = (bf16)v.z; o.w = (bf16)v.w;
  ((bf16x4*)xb)[i] = o;
}

// ------- transpose+cast weights: W[k][n] fp32 -> Wt[n][k] bf16 -------
__global__ void twcast_kernel(const float* __restrict__ w0, const float* __restrict__ w1,
                              const float* __restrict__ w2, const float* __restrict__ w3,
                              bf16* __restrict__ o0, bf16* __restrict__ o1,
                              bf16* __restrict__ o2, bf16* __restrict__ o3) {
  int z = blockIdx.z;
  const float* W = (z == 0) ? w0 : (z == 1) ? w1 : (z == 2) ? w2 : w3;
  bf16* O = (z == 0) ? o0 : (z == 1) ? o1 : (z == 2) ? o2 : o3;
  __shared__ float tile[64][65];
  int t = threadIdx.x, tx = t & 15, ty = t >> 4;
  int n0 = blockIdx.x * 64, k0 = blockIdx.y * 64;
#pragma unroll
  for (int i = 0; i < 4; i++) {
    float4 v = *(const float4*)&W[(size_t)(k0 + ty + i * 16) * D_ + n0 + tx * 4];
    tile[ty + i * 16][tx * 4 + 0] = v.x;
    tile[ty + i * 16][tx * 4 + 1] = v.y;
    tile[ty + i * 16][tx * 4 + 2] = v.z;
    tile[ty + i * 16][tx * 4 + 3] = v.w;
  }
  __syncthreads();
#pragma unroll
  for (int i = 0; i < 4; i++) {
    int n = ty + i * 16;
    bf16x4 o;
    o.x = (bf16)tile[tx * 4 + 0][n];
    o.y = (bf16)tile[tx * 4 + 1][n];
    o.z = (bf16)tile[tx * 4 + 2][n];
    o.w = (bf16)tile[tx * 4 + 3][n];
    *(bf16x4*)&O[(size_t)(n0 + n) * D_ + k0 + tx * 4] = o;
  }
}

// ------- stage one 128x64 bf16 k-slab of A and B into (swizzled) LDS -------
__device__ __forceinline__ void stage_tile(const bf16* __restrict__ A,
                                           const bf16* __restrict__ Bt,
                                           char* aT, char* bT,
                                           int m0, int n0, int k0, int t) {
#pragma unroll
  for (int i = 0; i < 4; i++) {
    int L = i * 4096 + t * 16;
    int row = L >> 7;
    int kb = (L & 127) ^ ((row & 7) << 4);  // inverse swizzle on source
    gload_lds16(A + (size_t)(m0 + row) * 2048 + k0 + (kb >> 1), aT + L);
    gload_lds16(Bt + (size_t)(n0 + row) * 2048 + k0 + (kb >> 1), bT + L);
  }
}

// ------- 128x128-tile GEMM core, 2-phase prefetch double-buffer -------
__device__ __forceinline__ void gemm_compute64(const char* aT, const char* bT,
                                               f32x4 acc[4][4], int lane, int wr, int wc) {
#pragma unroll
  for (int kk = 0; kk < 2; kk++) {
    int ak = kk * 64 + ((lane >> 4) << 4);
    bf16x8 af[4], bfv[4];
#pragma unroll
    for (int f = 0; f < 4; f++) {
      int ar = wr * 64 + f * 16 + (lane & 15);
      af[f] = *(const bf16x8*)(aT + ar * 128 + (ak ^ ((ar & 7) << 4)));
      int br = wc * 64 + f * 16 + (lane & 15);
      bfv[f] = *(const bf16x8*)(bT + br * 128 + (ak ^ ((br & 7) << 4)));
    }
#pragma unroll
    for (int mi = 0; mi < 4; mi++)
#pragma unroll
      for (int ni = 0; ni < 4; ni++)
        acc[mi][ni] = __builtin_amdgcn_mfma_f32_16x16x32_bf16(af[mi], bfv[ni], acc[mi][ni], 0, 0, 0);
  }
}

__device__ __forceinline__ void gemm_core_128(const bf16* __restrict__ A,
                                              const bf16* __restrict__ Bt,
                                              f32x4 acc[4][4], int m0, int n0) {
  __shared__ char smem[65536];  // 2 x (A 16K + B 16K)
  const int t = threadIdx.x;
  const int lane = t & 63;
  const int wr = (t >> 7) & 1;
  const int wc = (t >> 6) & 1;
  stage_tile(A, Bt, smem, smem + 16384, m0, n0, 0, t);
  __syncthreads();  // drains vmcnt
  int cur = 0;
  for (int k0 = 64; k0 < 2048; k0 += 64) {
    char* base = smem + (cur ^ 1) * 32768;
    stage_tile(A, Bt, base, base + 16384, m0, n0, k0, t);  // prefetch next
    char* cbase = smem + cur * 32768;
    gemm_compute64(cbase, cbase + 16384, acc, lane, wr, wc);
    __syncthreads();  // drain prefetch + all waves done reading cur
    cur ^= 1;
  }
  char* cbase = smem + cur * 32768;
  gemm_compute64(cbase, cbase + 16384, acc, lane, wr, wc);
}

// ------- QKV projection -------
// z=0: Q -> [bh][t][hd] bf16, scaled by SCALE*LOG2E (exp2-domain softmax)
// z=1: K -> [bh][t][hd] bf16
// z=2: V -> written DIRECTLY transposed as Vt [bh][hd][t] bf16 (vtr fused away)
__global__ __launch_bounds__(256, 2) void qkv_gemm_kernel(
    const bf16* __restrict__ xb,
    const bf16* __restrict__ wqt, const bf16* __restrict__ wkt, const bf16* __restrict__ wvt,
    const float* __restrict__ bq, const float* __restrict__ bk, const float* __restrict__ bv,
    bf16* __restrict__ Qb, bf16* __restrict__ Kb, bf16* __restrict__ Vtb) {
  const bf16* Bt; const float* bias; float scale;
  int z = blockIdx.z;
  if (z == 0)      { Bt = wqt; bias = bq; scale = SCALE_ * LOG2E_; }
  else if (z == 1) { Bt = wkt; bias = bk; scale = 1.0f; }
  else             { Bt = wvt; bias = bv; scale = 1.0f; }
  int m0 = blockIdx.y * 128, n0 = blockIdx.x * 128;
  f32x4 zero = {0.f, 0.f, 0.f, 0.f};
  f32x4 acc[4][4];
#pragma unroll
  for (int mi = 0; mi < 4; mi++)
#pragma unroll
    for (int ni = 0; ni < 4; ni++) acc[mi][ni] = zero;
  gemm_core_128(xb, Bt, acc, m0, n0);
  int lane = threadIdx.x & 63;
  int wr = (threadIdx.x >> 7) & 1, wc = (threadIdx.x >> 6) & 1;
  if (z < 2) {
    bf16* Out = (z == 0) ? Qb : Kb;
#pragma unroll
    for (int ni = 0; ni < 4; ni++) {
      int cn = n0 + wc * 64 + ni * 16 + (lane & 15);
      float bb = bias[cn];
      int h = cn >> 7, hd = cn & 127;
#pragma unroll
      for (int mi = 0; mi < 4; mi++) {
        int rm = m0 + wr * 64 + mi * 16 + ((lane >> 4) << 2);
#pragma unroll
        for (int r = 0; r < 4; r++) {
          int mg = rm + r;
          int b = mg >> 11, tt = mg & 2047;
          Out[(size_t)((b * H_ + h) * T_ + tt) * HD_ + hd] = (bf16)((acc[mi][ni][r] + bb) * scale);
        }
      }
    }
  } else {
    // V: write transposed [bh][hd][t]; r indexes 4 consecutive tokens -> bf16x4
#pragma unroll
    for (int ni = 0; ni < 4; ni++) {
      int cn = n0 + wc * 64 + ni * 16 + (lane & 15);
      float bb = bias[cn];
      int h = cn >> 7, hd = cn & 127;
#pragma unroll
      for (int mi = 0; mi < 4; mi++) {
        int rm = m0 + wr * 64 + mi * 16 + ((lane >> 4) << 2);
        int b = rm >> 11, tt = rm & 2047;
        bf16x4 st;
        st.x = (bf16)(acc[mi][ni][0] + bb);
        st.y = (bf16)(acc[mi][ni][1] + bb);
        st.z = (bf16)(acc[mi][ni][2] + bb);
        st.w = (bf16)(acc[mi][ni][3] + bb);
        *(bf16x4*)&Vtb[((size_t)(b * H_ + h) * HD_ + hd) * T_ + tt] = st;
      }
    }
  }
}

// ------- flash attention v3: swapped-operand 32x32 MFMA, in-register softmax,
//         double-buffered K/V staging, XCD-aware block swizzle -------
// Per block: 4 waves x 32 q-rows (QBLK=128), KVBLK=64; 64KB LDS -> 2 blocks/CU.
__global__ __launch_bounds__(256, 2) void attn_kernel(
    const bf16* __restrict__ Qb, const bf16* __restrict__ Kb,
    const bf16* __restrict__ Vtb, bf16* __restrict__ Ab) {
  __shared__ char smem[65536];  // 2 x (K 16K + Vt 16K)
  const int t = threadIdx.x, lane = t & 63, w = t >> 6;
  const int h0 = lane >> 5;    // which 32-lane half
  const int q = lane & 31;     // this lane's q-column (within wave's 32 rows)
  // XCD swizzle: 512 blocks, 8 XCDs -> each XCD owns 64 contiguous work ids
  // (4 heads' worth) so K/V panels stay in one XCD's L2.
  int bid = blockIdx.x;
  int wid = (bid & 7) * 64 + (bid >> 3);
  const int bh = wid >> 4;
  const int q0 = (wid & 15) * 128;
  const bf16* Qh = Qb + (size_t)bh * T_ * HD_;
  const bf16* Kh = Kb + (size_t)bh * T_ * HD_;
  const bf16* Vh = Vtb + (size_t)bh * HD_ * T_;

  // Q as MFMA B-operand: col=q, rows hd = kf*16 + h0*8 + j (8 consecutive)
  bf16x8 qf[8];
  {
    const bf16* qrow = Qh + (size_t)(q0 + w * 32 + q) * HD_ + h0 * 8;
#pragma unroll
    for (int kf = 0; kf < 8; kf++) qf[kf] = *(const bf16x8*)(qrow + kf * 16);
  }

  f32x16 o[4];  // O^T: o[nb] rows d = nb*32 + (r&3)+8*(r>>2)+4*h0, col q
#pragma unroll
  for (int nb = 0; nb < 4; nb++)
#pragma unroll
    for (int r = 0; r < 16; r++) o[nb][r] = 0.f;
  float m = -1e30f, l = 0.f;

  // stage K [64][128] / Vt [128][64] tile kt into buffer (pre-swizzled source)
  auto stage = [&](int kt, char* Kl, char* Vl) {
#pragma unroll
    for (int i = 0; i < 4; i++) {
      int L = i * 4096 + t * 16;
      int rowK = L >> 8;
      int kbK = (L & 255) ^ ((rowK & 7) << 4);
      gload_lds16(Kh + (size_t)(kt + rowK) * HD_ + (kbK >> 1), Kl + L);
      int rowV = L >> 7;
      int kbV = (L & 127) ^ ((rowV & 7) << 4);
      gload_lds16(Vh + (size_t)rowV * T_ + kt + (kbV >> 1), Vl + L);
    }
  };

  stage(0, smem, smem + 16384);
  __syncthreads();  // drain initial stage
  int cur = 0;

  for (int kt = 0; kt < T_; kt += 64) {
    char* Klds = smem + cur * 32768;
    char* Vlds = Klds + 16384;
    if (kt + 64 < T_) {  // prefetch next tile into other buffer
      char* nxt = smem + (cur ^ 1) * 32768;
      stage(kt + 64, nxt, nxt + 16384);
    }

    // S^T[k][q]: 2 k-subtiles of 32, K-dim = hd in 8 slices of 16
    f32x16 s[2];
#pragma unroll
    for (int sub = 0; sub < 2; sub++)
#pragma unroll
      for (int r = 0; r < 16; r++) s[sub][r] = 0.f;
#pragma unroll
    for (int kf = 0; kf < 8; kf++) {
#pragma unroll
      for (int sub = 0; sub < 2; sub++) {
        int rr = sub * 32 + q;
        bf16x8 kfr = *(const bf16x8*)(Klds + rr * 256 + ((kf * 32 + h0 * 16) ^ ((rr & 7) << 4)));
        s[sub] = __builtin_amdgcn_mfma_f32_32x32x16_bf16(kfr, qf[kf], s[sub], 0, 0, 0);
      }
    }

    // row softmax: 32 scores in-lane + 32 on lane^32 (exp2 domain, Q pre-scaled)
    float mx = s[0][0];
#pragma unroll
    for (int sub = 0; sub < 2; sub++)
#pragma unroll
      for (int r = 0; r < 16; r++) mx = fmaxf(mx, s[sub][r]);
    mx = fmaxf(mx, __shfl_xor(mx, 32));
    if (__any(mx > m + 8.f)) {  // defer-max (T13): rescale rarely
      float mn = fmaxf(m, mx);
      float fac = exp2f(m - mn);
      m = mn;
      l *= fac;
#pragma unroll
      for (int nb = 0; nb < 4; nb++)
#pragma unroll
        for (int r = 0; r < 16; r++) o[nb][r] *= fac;
    }
    float rs = 0.f;
#pragma unroll
    for (int sub = 0; sub < 2; sub++)
#pragma unroll
      for (int r = 0; r < 16; r++) {
        float p = exp2f(s[sub][r] - m);
        s[sub][r] = p;
        rs += p;
      }
    rs += __shfl_xor(rs, 32);
    l += rs;

    // pack P -> bf16 B-operand frags: pfrag[ks] holds k = 16*ks + 8*h0 + j
    bf16x8 pfrag[4];
#pragma unroll
    for (int sub = 0; sub < 2; sub++) {
#pragma unroll
      for (int c = 0; c < 2; c++) {
        u32 X0 = packbf(s[sub][8 * c + 0], s[sub][8 * c + 1]);
        u32 X1 = packbf(s[sub][8 * c + 2], s[sub][8 * c + 3]);
        u32 Y0 = packbf(s[sub][8 * c + 4], s[sub][8 * c + 5]);
        u32 Y1 = packbf(s[sub][8 * c + 6], s[sub][8 * c + 7]);
        u32 sX0 = (u32)__shfl_xor((int)X0, 32);
        u32 sX1 = (u32)__shfl_xor((int)X1, 32);
        u32 sY0 = (u32)__shfl_xor((int)Y0, 32);
        u32 sY1 = (u32)__shfl_xor((int)Y1, 32);
        u32x4 wv;
        wv.x = h0 ? sY0 : X0;  // elems j=0,1
        wv.y = h0 ? sY1 : X1;  // j=2,3
        wv.z = h0 ? Y0 : sX0;  // j=4,5
        wv.w = h0 ? Y1 : sX1;  // j=6,7
        union { u32x4 u; bf16x8 b; } cv;
        cv.u = wv;
        pfrag[sub * 2 + c] = cv.b;
      }
    }

    // O^T += V^T P : A = V^T frag (rows d), B = P frag
#pragma unroll
    for (int nb = 0; nb < 4; nb++) {
      int vr = nb * 32 + q;
#pragma unroll
      for (int ks = 0; ks < 4; ks++) {
        bf16x8 vf = *(const bf16x8*)(Vlds + vr * 128 + ((ks * 32 + h0 * 16) ^ ((vr & 7) << 4)));
        o[nb] = __builtin_amdgcn_mfma_f32_32x32x16_bf16(vf, pfrag[ks], o[nb], 0, 0, 0);
      }
    }
    __syncthreads();  // prefetch landed + all waves done reading cur
    cur ^= 1;
  }

  // normalize (per-lane: all o regs belong to q-col q) and write
  float inv = 1.f / l;
  int b = bh >> 4, hh = bh & 15;
  bf16* orow = Ab + ((size_t)b * T_ + q0 + w * 32 + q) * D_ + hh * HD_;
#pragma unroll
  for (int nb = 0; nb < 4; nb++)
#pragma unroll
    for (int g = 0; g < 4; g++) {
      bf16x4 st;
      st.x = (bf16)(o[nb][4 * g + 0] * inv);
      st.y = (bf16)(o[nb][4 * g + 1] * inv);
      st.z = (bf16)(o[nb][4 * g + 2] * inv);
      st.w = (bf16)(o[nb][4 * g + 3] * inv);
      *(bf16x4*)(orow + nb * 32 + 8 * g + 4 * h0) = st;
    }
}

// ------- output projection: out = attn @ wo + bo (fp32 out) -------
__global__ __launch_bounds__(256, 2) void out_gemm_kernel(
    const bf16* __restrict__ Ab, const bf16* __restrict__ wot,
    const float* __restrict__ bo, float* __restrict__ out) {
  int m0 = blockIdx.y * 128, n0 = blockIdx.x * 128;
  f32x4 zero = {0.f, 0.f, 0.f, 0.f};
  f32x4 acc[4][4];
#pragma unroll
  for (int mi = 0; mi < 4; mi++)
#pragma unroll
    for (int ni = 0; ni < 4; ni++) acc[mi][ni] = zero;
  gemm_core_128(Ab, wot, acc, m0, n0);
  int lane = threadIdx.x & 63;
  int wr = (threadIdx.x >> 7) & 1, wc = (threadIdx.x >> 6) & 1;
#pragma unroll
  for (int ni = 0; ni < 4; ni++) {
    int cn = n0 + wc * 64 + ni * 16 + (lane & 15);
    float bb = bo[cn];
#pragma unroll
    for (int mi = 0; mi < 4; mi++) {
      int rm = m0 + wr * 64 + mi * 16 + ((lane >> 4) << 2);
#pragma unroll
      for (int r = 0; r < 4; r++)
        out[(size_t)(rm + r) * D_ + cn] = acc[mi][ni][r] + bb;
    }
  }
}

extern "C" void kernel_launch(void* const* d_in, const int* in_sizes, int n_in,
                              void* d_out, int out_size, void* d_ws, size_t ws_size,
                              hipStream_t stream) {
  const float* x  = (const float*)d_in[0];
  const float* wq = (const float*)d_in[1];
  const float* bq = (const float*)d_in[2];
  const float* wk = (const float*)d_in[3];
  const float* bk = (const float*)d_in[4];
  const float* wv = (const float*)d_in[5];
  const float* bv = (const float*)d_in[6];
  const float* wo = (const float*)d_in[7];
  const float* bo = (const float*)d_in[8];
  float* out = (float*)d_out;
  char* ws = (char*)d_ws;

  bf16* xb  = (bf16*)(ws);               // 16 MB  [4096][2048]
  bf16* wqt = (bf16*)(ws + 16777216);    // 8 MB   [n][k]
  bf16* wkt = (bf16*)(ws + 25165824);
  bf16* wvt = (bf16*)(ws + 33554432);
  bf16* wot = (bf16*)(ws + 41943040);
  bf16* Qb  = (bf16*)(ws + 50331648);    // 16 MB  [bh][t][hd] (SCALE*LOG2E folded)
  bf16* Kb  = (bf16*)(ws + 67108864);    // 16 MB  [bh][t][hd]
  bf16* Vtb = (bf16*)(ws + 83886080);    // 16 MB  [bh][hd][t] (written directly by qkv)
  bf16* Ab  = xb;  // xb dead after qkv_gemm; reuse for attention output

  cast_x_kernel<<<8192, 256, 0, stream>>>(x, xb);
  twcast_kernel<<<dim3(32, 32, 4), 256, 0, stream>>>(wq, wk, wv, wo, wqt, wkt, wvt, wot);
  qkv_gemm_kernel<<<dim3(16, 32, 3), 256, 0, stream>>>(xb, wqt, wkt, wvt, bq, bk, bv, Qb, Kb, Vtb);
  attn_kernel<<<512, 256, 0, stream>>>(Qb, Kb, Vtb, Ab);
  out_gemm_kernel<<<dim3(16, 32), 256, 0, stream>>>(Ab, wot, bo, out);

  (void)in_sizes; (void)n_in; (void)out_size; (void)ws_size;
}

// Round 6
// 384.489 us; speedup vs baseline: 1.0335x; 1.0335x over previous
//
#include <hip/hip_runtime.h>

typedef unsigned int u32;
typedef __bf16 bf16;
typedef bf16 bf16x2 __attribute__((ext_vector_type(2)));
typedef bf16 bf16x4 __attribute__((ext_vector_type(4)));
typedef bf16 bf16x8 __attribute__((ext_vector_type(8)));
typedef float f32x4 __attribute__((ext_vector_type(4)));
typedef float f32x16 __attribute__((ext_vector_type(16)));
typedef u32 u32x4 __attribute__((ext_vector_type(4)));

#define T_ 2048
#define D_ 2048
#define H_ 16
#define HD_ 128
#define SCALE_ 0.022097086912079608f  // 2048^-0.5 (full embed_dim per reference)
#define LOG2E_ 1.4426950408889634f

typedef __attribute__((address_space(1))) u32 gu32;
typedef __attribute__((address_space(3))) u32 lu32;

__device__ __forceinline__ void gload_lds16(const void* g, void* l) {
  __builtin_amdgcn_global_load_lds((gu32*)(void*)g, (lu32*)l, 16, 0, 0);
}

__device__ __forceinline__ u32 packbf(float a, float b) {
  union { bf16x2 v; u32 u; } c;
  c.v.x = (bf16)a; c.v.y = (bf16)b;
  return c.u;
}

// ------- prep: z<4 transpose+cast W[k][n] fp32 -> Wt[n][k] bf16; z==4 cast x -------
__global__ void prep_kernel(const float* __restrict__ x, bf16* __restrict__ xb,
                            const float* __restrict__ w0, const float* __restrict__ w1,
                            const float* __restrict__ w2, const float* __restrict__ w3,
                            bf16* __restrict__ o0, bf16* __restrict__ o1,
                            bf16* __restrict__ o2, bf16* __restrict__ o3) {
  int z = blockIdx.z;
  int t = threadIdx.x;
  if (z == 4) {
    // cast x: 8M floats; 1024 blocks x 256 thr x 8 float4
    int b2 = blockIdx.y * 32 + blockIdx.x;
#pragma unroll
    for (int j = 0; j < 8; j++) {
      int i = b2 * 2048 + j * 256 + t;
      float4 v = ((const float4*)x)[i];
      bf16x4 o;
      o.x = (bf16)v.x; o.y = (bf16)v.y; o.z = (bf16)v.z; o.w = (bf16)v.w;
      ((bf16x4*)xb)[i] = o;
    }
    return;
  }
  const float* W = (z == 0) ? w0 : (z == 1) ? w1 : (z == 2) ? w2 : w3;
  bf16* O = (z == 0) ? o0 : (z == 1) ? o1 : (z == 2) ? o2 : o3;
  __shared__ float tile[64][65];
  int tx = t & 15, ty = t >> 4;
  int n0 = blockIdx.x * 64, k0 = blockIdx.y * 64;
#pragma unroll
  for (int i = 0; i < 4; i++) {
    float4 v = *(const float4*)&W[(size_t)(k0 + ty + i * 16) * D_ + n0 + tx * 4];
    tile[ty + i * 16][tx * 4 + 0] = v.x;
    tile[ty + i * 16][tx * 4 + 1] = v.y;
    tile[ty + i * 16][tx * 4 + 2] = v.z;
    tile[ty + i * 16][tx * 4 + 3] = v.w;
  }
  __syncthreads();
#pragma unroll
  for (int i = 0; i < 4; i++) {
    int n = ty + i * 16;
    bf16x4 o;
    o.x = (bf16)tile[tx * 4 + 0][n];
    o.y = (bf16)tile[tx * 4 + 1][n];
    o.z = (bf16)tile[tx * 4 + 2][n];
    o.w = (bf16)tile[tx * 4 + 3][n];
    *(bf16x4*)&O[(size_t)(n0 + n) * D_ + k0 + tx * 4] = o;
  }
}

// ------- stage one 128x64 bf16 k-slab of A and B into (swizzled) LDS -------
__device__ __forceinline__ void stage_tile(const bf16* __restrict__ A,
                                           const bf16* __restrict__ Bt,
                                           char* aT, char* bT,
                                           int m0, int n0, int k0, int t) {
#pragma unroll
  for (int i = 0; i < 4; i++) {
    int L = i * 4096 + t * 16;
    int row = L >> 7;
    int kb = (L & 127) ^ ((row & 7) << 4);  // inverse swizzle on source
    gload_lds16(A + (size_t)(m0 + row) * 2048 + k0 + (kb >> 1), aT + L);
    gload_lds16(Bt + (size_t)(n0 + row) * 2048 + k0 + (kb >> 1), bT + L);
  }
}

// ------- 128x128-tile GEMM core, 2-phase prefetch double-buffer -------
__device__ __forceinline__ void gemm_compute64(const char* aT, const char* bT,
                                               f32x4 acc[4][4], int lane, int wr, int wc) {
#pragma unroll
  for (int kk = 0; kk < 2; kk++) {
    int ak = kk * 64 + ((lane >> 4) << 4);
    bf16x8 af[4], bfv[4];
#pragma unroll
    for (int f = 0; f < 4; f++) {
      int ar = wr * 64 + f * 16 + (lane & 15);
      af[f] = *(const bf16x8*)(aT + ar * 128 + (ak ^ ((ar & 7) << 4)));
      int br = wc * 64 + f * 16 + (lane & 15);
      bfv[f] = *(const bf16x8*)(bT + br * 128 + (ak ^ ((br & 7) << 4)));
    }
#pragma unroll
    for (int mi = 0; mi < 4; mi++)
#pragma unroll
      for (int ni = 0; ni < 4; ni++)
        acc[mi][ni] = __builtin_amdgcn_mfma_f32_16x16x32_bf16(af[mi], bfv[ni], acc[mi][ni], 0, 0, 0);
  }
}

__device__ __forceinline__ void gemm_core_128(const bf16* __restrict__ A,
                                              const bf16* __restrict__ Bt,
                                              f32x4 acc[4][4], int m0, int n0) {
  __shared__ char smem[65536];  // 2 x (A 16K + B 16K)
  const int t = threadIdx.x;
  const int lane = t & 63;
  const int wr = (t >> 7) & 1;
  const int wc = (t >> 6) & 1;
  stage_tile(A, Bt, smem, smem + 16384, m0, n0, 0, t);
  __syncthreads();  // drains vmcnt
  int cur = 0;
  for (int k0 = 64; k0 < 2048; k0 += 64) {
    char* base = smem + (cur ^ 1) * 32768;
    stage_tile(A, Bt, base, base + 16384, m0, n0, k0, t);  // prefetch next
    char* cbase = smem + cur * 32768;
    gemm_compute64(cbase, cbase + 16384, acc, lane, wr, wc);
    __syncthreads();  // drain prefetch + all waves done reading cur
    cur ^= 1;
  }
  char* cbase = smem + cur * 32768;
  gemm_compute64(cbase, cbase + 16384, acc, lane, wr, wc);
}

// ------- QKV projection (XCD-chunked 1-D grid) -------
// z=0: Q -> [bh][t][hd] bf16, scaled by SCALE*LOG2E; z=1: K; z=2: V transposed [bh][hd][t]
__global__ __launch_bounds__(256, 2) void qkv_gemm_kernel(
    const bf16* __restrict__ xb,
    const bf16* __restrict__ wqt, const bf16* __restrict__ wkt, const bf16* __restrict__ wvt,
    const float* __restrict__ bq, const float* __restrict__ bk, const float* __restrict__ bv,
    bf16* __restrict__ Qb, bf16* __restrict__ Kb, bf16* __restrict__ Vtb) {
  const bf16* Bt; const float* bias; float scale;
  int z = blockIdx.z;
  if (z == 0)      { Bt = wqt; bias = bq; scale = SCALE_ * LOG2E_; }
  else if (z == 1) { Bt = wkt; bias = bk; scale = 1.0f; }
  else             { Bt = wvt; bias = bv; scale = 1.0f; }
  // XCD swizzle: 512 tiles -> each XCD owns 64 contiguous (4 A-panels, 2MB L2-fit)
  int bid = blockIdx.x;
  int wid = (bid & 7) * 64 + (bid >> 3);
  int n0 = (wid & 15) * 128, m0 = (wid >> 4) * 128;
  f32x4 zero = {0.f, 0.f, 0.f, 0.f};
  f32x4 acc[4][4];
#pragma unroll
  for (int mi = 0; mi < 4; mi++)
#pragma unroll
    for (int ni = 0; ni < 4; ni++) acc[mi][ni] = zero;
  gemm_core_128(xb, Bt, acc, m0, n0);
  int lane = threadIdx.x & 63;
  int wr = (threadIdx.x >> 7) & 1, wc = (threadIdx.x >> 6) & 1;
  if (z < 2) {
    bf16* Out = (z == 0) ? Qb : Kb;
#pragma unroll
    for (int ni = 0; ni < 4; ni++) {
      int cn = n0 + wc * 64 + ni * 16 + (lane & 15);
      float bb = bias[cn];
      int h = cn >> 7, hd = cn & 127;
#pragma unroll
      for (int mi = 0; mi < 4; mi++) {
        int rm = m0 + wr * 64 + mi * 16 + ((lane >> 4) << 2);
#pragma unroll
        for (int r = 0; r < 4; r++) {
          int mg = rm + r;
          int b = mg >> 11, tt = mg & 2047;
          Out[(size_t)((b * H_ + h) * T_ + tt) * HD_ + hd] = (bf16)((acc[mi][ni][r] + bb) * scale);
        }
      }
    }
  } else {
    // V: write transposed [bh][hd][t]; r indexes 4 consecutive tokens -> bf16x4
#pragma unroll
    for (int ni = 0; ni < 4; ni++) {
      int cn = n0 + wc * 64 + ni * 16 + (lane & 15);
      float bb = bias[cn];
      int h = cn >> 7, hd = cn & 127;
#pragma unroll
      for (int mi = 0; mi < 4; mi++) {
        int rm = m0 + wr * 64 + mi * 16 + ((lane >> 4) << 2);
        int b = rm >> 11, tt = rm & 2047;
        bf16x4 st;
        st.x = (bf16)(acc[mi][ni][0] + bb);
        st.y = (bf16)(acc[mi][ni][1] + bb);
        st.z = (bf16)(acc[mi][ni][2] + bb);
        st.w = (bf16)(acc[mi][ni][3] + bb);
        *(bf16x4*)&Vtb[((size_t)(b * H_ + h) * HD_ + hd) * T_ + tt] = st;
      }
    }
  }
}

// ------- flash attention v4: swapped-operand 32x32 MFMA, in-register softmax,
//         dbuf K/V staging, XCD swizzle, setprio, hoisted swizzle offsets -------
__global__ __launch_bounds__(256, 2) void attn_kernel(
    const bf16* __restrict__ Qb, const bf16* __restrict__ Kb,
    const bf16* __restrict__ Vtb, bf16* __restrict__ Ab) {
  __shared__ char smem[65536];  // 2 x (K 16K + Vt 16K)
  const int t = threadIdx.x, lane = t & 63, w = t >> 6;
  const int h0 = lane >> 5;    // which 32-lane half
  const int q = lane & 31;     // this lane's q-column (within wave's 32 rows)
  int bid = blockIdx.x;
  int wid = (bid & 7) * 64 + (bid >> 3);
  const int bh = wid >> 4;
  const int q0 = (wid & 15) * 128;
  const bf16* Qh = Qb + (size_t)bh * T_ * HD_;
  const bf16* Kh = Kb + (size_t)bh * T_ * HD_;
  const bf16* Vh = Vtb + (size_t)bh * HD_ * T_;

  // hoisted per-lane swizzled LDS read offsets: (rr&7)==(q&7) for all rows used
  int soff[8];
#pragma unroll
  for (int kf = 0; kf < 8; kf++) soff[kf] = (kf * 32 + h0 * 16) ^ ((q & 7) << 4);
  const int kbase = q * 256;  // K row base (row = sub*32+q; sub via +8192 imm)
  const int vbase = q * 128;  // V row base (row = nb*32+q; nb via +4096 imm)

  // Q as MFMA B-operand: col=q, rows hd = kf*16 + h0*8 + j (8 consecutive)
  bf16x8 qf[8];
  {
    const bf16* qrow = Qh + (size_t)(q0 + w * 32 + q) * HD_ + h0 * 8;
#pragma unroll
    for (int kf = 0; kf < 8; kf++) qf[kf] = *(const bf16x8*)(qrow + kf * 16);
  }

  f32x16 o[4];  // O^T: o[nb] rows d = nb*32 + (r&3)+8*(r>>2)+4*h0, col q
#pragma unroll
  for (int nb = 0; nb < 4; nb++)
#pragma unroll
    for (int r = 0; r < 16; r++) o[nb][r] = 0.f;
  float m = -1e30f, l = 0.f;

  auto stage = [&](int kt, char* Kl, char* Vl) {
#pragma unroll
    for (int i = 0; i < 4; i++) {
      int L = i * 4096 + t * 16;
      int rowK = L >> 8;
      int kbK = (L & 255) ^ ((rowK & 7) << 4);
      gload_lds16(Kh + (size_t)(kt + rowK) * HD_ + (kbK >> 1), Kl + L);
      int rowV = L >> 7;
      int kbV = (L & 127) ^ ((rowV & 7) << 4);
      gload_lds16(Vh + (size_t)rowV * T_ + kt + (kbV >> 1), Vl + L);
    }
  };

  stage(0, smem, smem + 16384);
  __syncthreads();  // drain initial stage
  int cur = 0;

  for (int kt = 0; kt < T_; kt += 64) {
    const char* Klds = smem + cur * 32768;
    const char* Vlds = Klds + 16384;
    if (kt + 64 < T_) {  // prefetch next tile into other buffer
      char* nxt = smem + (cur ^ 1) * 32768;
      stage(kt + 64, nxt, nxt + 16384);
    }

    // S^T[k][q]: 2 k-subtiles of 32, K-dim = hd in 8 slices of 16
    f32x16 s[2];
#pragma unroll
    for (int sub = 0; sub < 2; sub++)
#pragma unroll
      for (int r = 0; r < 16; r++) s[sub][r] = 0.f;
    __builtin_amdgcn_s_setprio(1);
#pragma unroll
    for (int kf = 0; kf < 8; kf++) {
#pragma unroll
      for (int sub = 0; sub < 2; sub++) {
        bf16x8 kfr = *(const bf16x8*)(Klds + kbase + sub * 8192 + soff[kf]);
        s[sub] = __builtin_amdgcn_mfma_f32_32x32x16_bf16(kfr, qf[kf], s[sub], 0, 0, 0);
      }
    }
    __builtin_amdgcn_s_setprio(0);

    // row softmax (exp2 domain, Q pre-scaled); max chain via v_max3 fusion
    float mx = fmaxf(s[0][0], s[0][1]);
#pragma unroll
    for (int sub = 0; sub < 2; sub++)
#pragma unroll
      for (int r = (sub == 0 ? 2 : 0); r < 16; r += 2)
        mx = fmaxf(mx, fmaxf(s[sub][r], s[sub][r + 1]));
    mx = fmaxf(mx, __shfl_xor(mx, 32));
    if (__any(mx > m + 8.f)) {  // defer-max (T13): rescale rarely
      float mn = fmaxf(m, mx);
      float fac = exp2f(m - mn);
      m = mn;
      l *= fac;
#pragma unroll
      for (int nb = 0; nb < 4; nb++)
#pragma unroll
        for (int r = 0; r < 16; r++) o[nb][r] *= fac;
    }
    float rs = 0.f;
#pragma unroll
    for (int sub = 0; sub < 2; sub++)
#pragma unroll
      for (int r = 0; r < 16; r++) {
        float p = exp2f(s[sub][r] - m);
        s[sub][r] = p;
        rs += p;
      }
    rs += __shfl_xor(rs, 32);
    l += rs;

    // pack P -> bf16 B-operand frags: pfrag[ks] holds k = 16*ks + 8*h0 + j
    bf16x8 pfrag[4];
#pragma unroll
    for (int sub = 0; sub < 2; sub++) {
#pragma unroll
      for (int c = 0; c < 2; c++) {
        u32 X0 = packbf(s[sub][8 * c + 0], s[sub][8 * c + 1]);
        u32 X1 = packbf(s[sub][8 * c + 2], s[sub][8 * c + 3]);
        u32 Y0 = packbf(s[sub][8 * c + 4], s[sub][8 * c + 5]);
        u32 Y1 = packbf(s[sub][8 * c + 6], s[sub][8 * c + 7]);
        u32 sX0 = (u32)__shfl_xor((int)X0, 32);
        u32 sX1 = (u32)__shfl_xor((int)X1, 32);
        u32 sY0 = (u32)__shfl_xor((int)Y0, 32);
        u32 sY1 = (u32)__shfl_xor((int)Y1, 32);
        u32x4 wv;
        wv.x = h0 ? sY0 : X0;  // elems j=0,1
        wv.y = h0 ? sY1 : X1;  // j=2,3
        wv.z = h0 ? Y0 : sX0;  // j=4,5
        wv.w = h0 ? Y1 : sX1;  // j=6,7
        union { u32x4 u; bf16x8 b; } cv;
        cv.u = wv;
        pfrag[sub * 2 + c] = cv.b;
      }
    }

    // O^T += V^T P : A = V^T frag (rows d), B = P frag
    __builtin_amdgcn_s_setprio(1);
#pragma unroll
    for (int nb = 0; nb < 4; nb++) {
#pragma unroll
      for (int ks = 0; ks < 4; ks++) {
        bf16x8 vf = *(const bf16x8*)(Vlds + vbase + nb * 4096 + soff[ks]);
        o[nb] = __builtin_amdgcn_mfma_f32_32x32x16_bf16(vf, pfrag[ks], o[nb], 0, 0, 0);
      }
    }
    __builtin_amdgcn_s_setprio(0);
    __syncthreads();  // prefetch landed + all waves done reading cur
    cur ^= 1;
  }

  // normalize (per-lane: all o regs belong to q-col q) and write
  float inv = 1.f / l;
  int b = bh >> 4, hh = bh & 15;
  bf16* orow = Ab + ((size_t)b * T_ + q0 + w * 32 + q) * D_ + hh * HD_;
#pragma unroll
  for (int nb = 0; nb < 4; nb++)
#pragma unroll
    for (int g = 0; g < 4; g++) {
      bf16x4 st;
      st.x = (bf16)(o[nb][4 * g + 0] * inv);
      st.y = (bf16)(o[nb][4 * g + 1] * inv);
      st.z = (bf16)(o[nb][4 * g + 2] * inv);
      st.w = (bf16)(o[nb][4 * g + 3] * inv);
      *(bf16x4*)(orow + nb * 32 + 8 * g + 4 * h0) = st;
    }
}

// ------- output projection: out = attn @ wo + bo (fp32 out), XCD-chunked -------
__global__ __launch_bounds__(256, 2) void out_gemm_kernel(
    const bf16* __restrict__ Ab, const bf16* __restrict__ wot,
    const float* __restrict__ bo, float* __restrict__ out) {
  int bid = blockIdx.x;
  int wid = (bid & 7) * 64 + (bid >> 3);
  int n0 = (wid & 15) * 128, m0 = (wid >> 4) * 128;
  f32x4 zero = {0.f, 0.f, 0.f, 0.f};
  f32x4 acc[4][4];
#pragma unroll
  for (int mi = 0; mi < 4; mi++)
#pragma unroll
    for (int ni = 0; ni < 4; ni++) acc[mi][ni] = zero;
  gemm_core_128(Ab, wot, acc, m0, n0);
  int lane = threadIdx.x & 63;
  int wr = (threadIdx.x >> 7) & 1, wc = (threadIdx.x >> 6) & 1;
#pragma unroll
  for (int ni = 0; ni < 4; ni++) {
    int cn = n0 + wc * 64 + ni * 16 + (lane & 15);
    float bb = bo[cn];
#pragma unroll
    for (int mi = 0; mi < 4; mi++) {
      int rm = m0 + wr * 64 + mi * 16 + ((lane >> 4) << 2);
#pragma unroll
      for (int r = 0; r < 4; r++)
        out[(size_t)(rm + r) * D_ + cn] = acc[mi][ni][r] + bb;
    }
  }
}

extern "C" void kernel_launch(void* const* d_in, const int* in_sizes, int n_in,
                              void* d_out, int out_size, void* d_ws, size_t ws_size,
                              hipStream_t stream) {
  const float* x  = (const float*)d_in[0];
  const float* wq = (const float*)d_in[1];
  const float* bq = (const float*)d_in[2];
  const float* wk = (const float*)d_in[3];
  const float* bk = (const float*)d_in[4];
  const float* wv = (const float*)d_in[5];
  const float* bv = (const float*)d_in[6];
  const float* wo = (const float*)d_in[7];
  const float* bo = (const float*)d_in[8];
  float* out = (float*)d_out;
  char* ws = (char*)d_ws;

  bf16* xb  = (bf16*)(ws);               // 16 MB  [4096][2048]
  bf16* wqt = (bf16*)(ws + 16777216);    // 8 MB   [n][k]
  bf16* wkt = (bf16*)(ws + 25165824);
  bf16* wvt = (bf16*)(ws + 33554432);
  bf16* wot = (bf16*)(ws + 41943040);
  bf16* Qb  = (bf16*)(ws + 50331648);    // 16 MB  [bh][t][hd] (SCALE*LOG2E folded)
  bf16* Kb  = (bf16*)(ws + 67108864);    // 16 MB  [bh][t][hd]
  bf16* Vtb = (bf16*)(ws + 83886080);    // 16 MB  [bh][hd][t] (written directly by qkv)
  bf16* Ab  = xb;  // xb dead after qkv_gemm; reuse for attention output

  prep_kernel<<<dim3(32, 32, 5), 256, 0, stream>>>(x, xb, wq, wk, wv, wo, wqt, wkt, wvt, wot);
  qkv_gemm_kernel<<<dim3(512, 1, 3), 256, 0, stream>>>(xb, wqt, wkt, wvt, bq, bk, bv, Qb, Kb, Vtb);
  attn_kernel<<<512, 256, 0, stream>>>(Qb, Kb, Vtb, Ab);
  out_gemm_kernel<<<512, 256, 0, stream>>>(Ab, wot, bo, out);

  (void)in_sizes; (void)n_in; (void)out_size; (void)ws_size;
}